// Round 9
// baseline (4126.296 us; speedup 1.0000x reference)
//
#include <hip/hip_runtime.h>
#include <hip/hip_fp16.h>
#include <math.h>

#define HD 1024          // hidden size H
#define BB 64            // batch B
#define TT 256           // seq len T
#define GG (3 * HD)      // 3H = 3072
#define NSCAN 64         // scan blocks (JPB=16)
#define NPROD 192        // xg producer blocks

typedef _Float16 f16x8 __attribute__((ext_vector_type(8)));
typedef float f32x4 __attribute__((ext_vector_type(4)));

// ---------------- ws layout (bytes) ----------------
// W_comb : [3072][1024] f32 @ 0           (12,582,912)
// b_comb : [3072] f32       @ 12,582,912  (12,288)
// xg     : [T][G][B] f32    @ 12,595,200  (201,326,592)  layout (t, g, b)
// hta    : fp16 [b][k]      @ 213,921,792 (131,072)      h state ping
// htb    : fp16 [b][k]      @ 214,052,864 (131,072)      pong
// hfin   : [k][b] f32       @ 214,183,936 (262,144)      final h
// bar    : @ 214,446,080: line0=root, lines1-8=grp, 9-16=rel (128B each);
//          cnt[256] u32 at +2176 (xg per-t ready counters, target 12)
static constexpr size_t OFF_WCOMB = 0;
static constexpr size_t OFF_BCOMB = 12582912;
static constexpr size_t OFF_XG    = 12595200;
static constexpr size_t OFF_HTA   = 213921792;
static constexpr size_t OFF_HTB   = 214052864;
static constexpr size_t OFF_HFIN  = 214183936;
static constexpr size_t OFF_BAR   = 214446080;

__device__ __forceinline__ float sigmoidf_(float x) {
    return 1.0f / (1.0f + expf(-x));
}

// -------------------------------------------------------------------------
// init: h0 (B,H) -> hta fp16 [b][k]; zero barrier+cnt
__global__ void k_init(const float* __restrict__ hidden, __half* __restrict__ hta,
                       unsigned* __restrict__ bar) {
    int idx = blockIdx.x * 256 + threadIdx.x;      // 65536 total
    hta[idx] = __float2half(hidden[idx]);
    if (idx < 17) bar[idx * 32] = 0u;
    if (idx < 256) bar[544 + idx] = 0u;
}

// -------------------------------------------------------------------------
// fold: W_comb[g][d] = sum_h W_ih[g][h] * W_in[h][d]
__global__ __launch_bounds__(256) void k_fold(const float* __restrict__ A,
                                              const float* __restrict__ Bw,
                                              float* __restrict__ C) {
    __shared__ __align__(16) float As[32][68];
    __shared__ __align__(16) float Bs[32][68];
    const int m0 = blockIdx.x * 64;
    const int n0 = blockIdx.y * 64;
    const int tid = threadIdx.x;
    const int r = (tid & 15) * 4;
    const int c = (tid >> 4) * 4;
    float acc[4][4] = {};
    for (int k0 = 0; k0 < HD; k0 += 32) {
        #pragma unroll
        for (int i = 0; i < 2; ++i) {
            int s = tid + i * 256;
            int row = s >> 3;
            int c4 = (s & 7) * 4;
            float4 v = *reinterpret_cast<const float4*>(&A[(size_t)(m0 + row) * HD + k0 + c4]);
            As[c4 + 0][row] = v.x; As[c4 + 1][row] = v.y;
            As[c4 + 2][row] = v.z; As[c4 + 3][row] = v.w;
        }
        #pragma unroll
        for (int i = 0; i < 2; ++i) {
            int s = tid + i * 256;
            int row = s >> 4;
            int c4 = (s & 15) * 4;
            float4 v = *reinterpret_cast<const float4*>(&Bw[(size_t)(k0 + row) * HD + n0 + c4]);
            *reinterpret_cast<float4*>(&Bs[row][c4]) = v;
        }
        __syncthreads();
        #pragma unroll
        for (int kk = 0; kk < 32; ++kk) {
            float4 av = *reinterpret_cast<const float4*>(&As[kk][r]);
            float4 bv = *reinterpret_cast<const float4*>(&Bs[kk][c]);
            float a_[4] = {av.x, av.y, av.z, av.w};
            float b_[4] = {bv.x, bv.y, bv.z, bv.w};
            #pragma unroll
            for (int i = 0; i < 4; ++i)
                #pragma unroll
                for (int j = 0; j < 4; ++j)
                    acc[i][j] += a_[i] * b_[j];
        }
        __syncthreads();
    }
    #pragma unroll
    for (int i = 0; i < 4; ++i) {
        float4 v = {acc[i][0], acc[i][1], acc[i][2], acc[i][3]};
        *reinterpret_cast<float4*>(&C[(size_t)(m0 + r + i) * HD + n0 + c]) = v;
    }
}

// -------------------------------------------------------------------------
__global__ void k_bcomb(const float* __restrict__ W_ih, const float* __restrict__ b_in,
                        const float* __restrict__ b_ih, float* __restrict__ b_comb) {
    int g = (blockIdx.x * blockDim.x + threadIdx.x) >> 6;
    int lane = threadIdx.x & 63;
    float s = 0.f;
    for (int k = lane; k < HD; k += 64) s += W_ih[(size_t)g * HD + k] * b_in[k];
    #pragma unroll
    for (int off = 32; off > 0; off >>= 1) s += __shfl_down(s, off);
    if (lane == 0) b_comb[g] = s + b_ih[g];
}

// -------------------------------------------------------------------------
// fused: blocks 0..63 = persistent MFMA GRU scan; blocks 64..255 = xg producers.
// v9: launch_bounds(512,1) so areg[32] (128 VGPR) stays in registers;
// split-k pipelined h staging (stage half1 global loads issued before MFMA on
// half0, LDS-written after); cred in separate LDS region; tighter barrier.
__global__ __launch_bounds__(512, 1) void k_fused(
        const float* __restrict__ Whh, const float* __restrict__ bhh,
        const float* __restrict__ wi,  const float* __restrict__ Wc,
        const float* __restrict__ bc,  float* __restrict__ xg,
        const float* __restrict__ hidden,
        __half* __restrict__ hta, __half* __restrict__ htb,
        float* __restrict__ hfin, unsigned* __restrict__ bar) {
    __shared__ __align__(16) char lds[144128];   // scan: lh 131072 + cred 13056
    const int tid = threadIdx.x;
    unsigned* const cnt = bar + 544;

    if (blockIdx.x < NSCAN) {
        // ---------------- scan role ----------------
        char* const lh = lds;                               // fp16 [64][1024] swizzled
        float* const cred = reinterpret_cast<float*>(lds + 131072);  // [48][68]
        const int bid = blockIdx.x;
        const int j0 = bid * 16;
        const int w  = tid >> 6;                      // wave 0..7
        const int l  = tid & 63;
        const int lg = l >> 4;                        // lane group 0..3
        const int ll = l & 15;
        const bool active = (w != 3 && w != 7);       // 6 working waves
        const int mt  = w & 3;                        // gate tile 0..2 (active)
        const int ntA = (w < 4) ? 0 : 1;
        const int ntB = ntA + 2;
        const int fb = tid >> 4;                      // 0..31
        const int fj = tid & 15;
        const int jg = j0 + fj;

        // A fragments: 32 kb x 8 halves, k-contiguous fill
        f16x8 areg[32];
        if (active) {
            const float* wrow = Whh + (size_t)(mt * HD + j0 + ll) * HD;
            #pragma unroll
            for (int kb = 0; kb < 32; ++kb) {
                int k0 = kb * 32 + lg * 8;
                float4 u0 = *reinterpret_cast<const float4*>(wrow + k0);
                float4 u1 = *reinterpret_cast<const float4*>(wrow + k0 + 4);
                f16x8 a;
                a[0] = (_Float16)u0.x; a[1] = (_Float16)u0.y;
                a[2] = (_Float16)u0.z; a[3] = (_Float16)u0.w;
                a[4] = (_Float16)u1.x; a[5] = (_Float16)u1.y;
                a[6] = (_Float16)u1.z; a[7] = (_Float16)u1.w;
                areg[kb] = a;
            }
        }
        const float br = bhh[jg], bz = bhh[HD + jg], bn = bhh[2 * HD + jg];
        float hold0 = hidden[(size_t)fb * HD + jg];
        float hold1 = hidden[(size_t)(fb + 32) * HD + jg];
        const int grp = bid >> 3;
        unsigned* const rootp = bar;
        unsigned* const grpp  = bar + 32 * (1 + grp);
        unsigned* const relp  = bar + 32 * (9 + grp);
        const int bA = ntA * 16 + ll, sA = bA & 7;
        const int bB = ntB * 16 + ll, sB = bB & 7;

        // gate for xg[0]
        if (tid == 0) {
            while (__hip_atomic_load(&cnt[0], __ATOMIC_RELAXED, __HIP_MEMORY_SCOPE_AGENT) < 12u)
                __builtin_amdgcn_s_sleep(1);
            (void)__hip_atomic_load(&cnt[0], __ATOMIC_ACQUIRE, __HIP_MEMORY_SCOPE_AGENT);
        }
        __syncthreads();

        for (int t = 0; t < TT; ++t) {
            const __half* hc = (t & 1) ? htb : hta;
            __half* hnx = (t & 1) ? hta : htb;
            // prefetch xg[t]
            const size_t tb = (size_t)t * GG * BB;
            float xr0 = xg[tb + (size_t)jg * BB + fb];
            float xz0 = xg[tb + (size_t)(HD + jg) * BB + fb];
            float xn0 = xg[tb + (size_t)(2 * HD + jg) * BB + fb];
            float xr1 = xg[tb + (size_t)jg * BB + fb + 32];
            float xz1 = xg[tb + (size_t)(HD + jg) * BB + fb + 32];
            float xn1 = xg[tb + (size_t)(2 * HD + jg) * BB + fb + 32];
            const char* hcB = reinterpret_cast<const char*>(hc);

            // ---- stage phase 0: k-chunks 0..63 (k 0..511) ----
            #pragma unroll
            for (int i = 0; i < 8; ++i) {
                int c = tid + i * 512;
                int row = c >> 6, kc = c & 63;
                float4 v = *reinterpret_cast<const float4*>(hcB + (size_t)row * 2048 + kc * 16);
                *reinterpret_cast<float4*>(lh + row * 2048 + ((kc ^ (row & 7)) << 4)) = v;
            }
            __syncthreads();

            // ---- issue phase-1 global loads (latency hides under MFMA-0) ----
            float4 pv[8];
            #pragma unroll
            for (int i = 0; i < 8; ++i) {
                int c = tid + i * 512;
                int row = c >> 6, kc = 64 + (c & 63);
                pv[i] = *reinterpret_cast<const float4*>(hcB + (size_t)row * 2048 + kc * 16);
            }
            // ---- MFMA phase 0 ----
            f32x4 acc0 = {0.f, 0.f, 0.f, 0.f}, acc1 = {0.f, 0.f, 0.f, 0.f};
            if (active) {
                #pragma unroll
                for (int kb = 0; kb < 16; ++kb) {
                    int kc = kb * 4 + lg;
                    f16x8 b0 = *reinterpret_cast<const f16x8*>(lh + bA * 2048 + ((kc ^ sA) << 4));
                    f16x8 b1 = *reinterpret_cast<const f16x8*>(lh + bB * 2048 + ((kc ^ sB) << 4));
                    acc0 = __builtin_amdgcn_mfma_f32_16x16x32_f16(areg[kb], b0, acc0, 0, 0, 0);
                    acc1 = __builtin_amdgcn_mfma_f32_16x16x32_f16(areg[kb], b1, acc1, 0, 0, 0);
                }
            }
            // ---- write phase-1 chunks to LDS ----
            #pragma unroll
            for (int i = 0; i < 8; ++i) {
                int c = tid + i * 512;
                int row = c >> 6, kc = 64 + (c & 63);
                *reinterpret_cast<float4*>(lh + row * 2048 + ((kc ^ (row & 7)) << 4)) = pv[i];
            }
            __syncthreads();
            // ---- MFMA phase 1 ----
            if (active) {
                #pragma unroll
                for (int kb = 16; kb < 32; ++kb) {
                    int kc = kb * 4 + lg;
                    f16x8 b0 = *reinterpret_cast<const f16x8*>(lh + bA * 2048 + ((kc ^ sA) << 4));
                    f16x8 b1 = *reinterpret_cast<const f16x8*>(lh + bB * 2048 + ((kc ^ sB) << 4));
                    acc0 = __builtin_amdgcn_mfma_f32_16x16x32_f16(areg[kb], b0, acc0, 0, 0, 0);
                    acc1 = __builtin_amdgcn_mfma_f32_16x16x32_f16(areg[kb], b1, acc1, 0, 0, 0);
                }
                int rb = mt * 16 + lg * 4;
                #pragma unroll
                for (int i = 0; i < 4; ++i) {
                    cred[(rb + i) * 68 + ntA * 16 + ll] = acc0[i];
                    cred[(rb + i) * 68 + ntB * 16 + ll] = acc1[i];
                }
            }
            __syncthreads();
            // ---- finalize 2 (j,b) pairs ----
            {
                float s0 = cred[fj * 68 + fb] + br;
                float s1 = cred[(16 + fj) * 68 + fb] + bz;
                float s2 = cred[(32 + fj) * 68 + fb] + bn;
                float rg = sigmoidf_(xr0 + s0);
                float zg = sigmoidf_(xz0 + s1);
                float ng = tanhf(xn0 + rg * s2);
                float hn0 = (1.0f - zg) * ng + zg * hold0;
                hold0 = hn0;
                hnx[(size_t)fb * HD + jg] = __float2half(hn0);
                float u0 = cred[fj * 68 + fb + 32] + br;
                float u1 = cred[(16 + fj) * 68 + fb + 32] + bz;
                float u2 = cred[(32 + fj) * 68 + fb + 32] + bn;
                float rg1 = sigmoidf_(xr1 + u0);
                float zg1 = sigmoidf_(xz1 + u1);
                float ng1 = tanhf(xn1 + rg1 * u2);
                float hn1 = (1.0f - zg1) * ng1 + zg1 * hold1;
                hold1 = hn1;
                hnx[(size_t)(fb + 32) * HD + jg] = __float2half(hn1);
                if (t == TT - 1) {
                    hfin[(size_t)jg * 64 + fb] = hn0;
                    hfin[(size_t)jg * 64 + fb + 32] = hn1;
                }
            }
            __syncthreads();   // h stores drained per-wave before tid0 release
            // tree barrier (+ xg[t+1] gate folded in before arrival)
            if (tid == 0) {
                const unsigned e = (unsigned)(t + 1);
                if (t + 1 < TT) {
                    while (__hip_atomic_load(&cnt[t + 1], __ATOMIC_RELAXED,
                                             __HIP_MEMORY_SCOPE_AGENT) < 12u)
                        __builtin_amdgcn_s_sleep(1);
                    (void)__hip_atomic_load(&cnt[t + 1], __ATOMIC_ACQUIRE,
                                            __HIP_MEMORY_SCOPE_AGENT);
                }
                unsigned old = __hip_atomic_fetch_add(grpp, 1u, __ATOMIC_ACQ_REL,
                                                      __HIP_MEMORY_SCOPE_AGENT);
                if (old == 8u * e - 1u) {
                    __hip_atomic_fetch_add(rootp, 1u, __ATOMIC_ACQ_REL,
                                           __HIP_MEMORY_SCOPE_AGENT);
                    while (__hip_atomic_load(rootp, __ATOMIC_RELAXED,
                                             __HIP_MEMORY_SCOPE_AGENT) < 8u * e) {}
                    (void)__hip_atomic_load(rootp, __ATOMIC_ACQUIRE, __HIP_MEMORY_SCOPE_AGENT);
                    __hip_atomic_store(relp, e, __ATOMIC_RELEASE, __HIP_MEMORY_SCOPE_AGENT);
                } else {
                    while (__hip_atomic_load(relp, __ATOMIC_RELAXED,
                                             __HIP_MEMORY_SCOPE_AGENT) < e) {}
                }
                (void)__hip_atomic_load(relp, __ATOMIC_ACQUIRE, __HIP_MEMORY_SCOPE_AGENT);
            }
            __syncthreads();
        }
    } else {
        // ---------------- xg producer role ----------------
        float* const As = reinterpret_cast<float*>(lds);          // [32][68]
        float* const Bs = reinterpret_cast<float*>(lds + 8704);   // [32][260]
        const int wid = blockIdx.x - NSCAN;                       // 0..191
        const int r = (tid & 7) * 8;     // b offset
        const int c = (tid >> 3) * 4;    // g offset
        for (int item = wid; item < TT * 12; item += NPROD) {
            const int t  = item / 12;
            const int g0 = (item % 12) * 256;
            float acc[8][4] = {};
            for (int k0 = 0; k0 < HD; k0 += 32) {
                {
                    int s = tid;                     // 512 chunks exactly
                    int row = s >> 3, c4 = (s & 7) * 4;
                    float4 v = *reinterpret_cast<const float4*>(
                        &wi[((size_t)row * TT + t) * HD + k0 + c4]);
                    As[(c4 + 0) * 68 + row] = v.x; As[(c4 + 1) * 68 + row] = v.y;
                    As[(c4 + 2) * 68 + row] = v.z; As[(c4 + 3) * 68 + row] = v.w;
                }
                #pragma unroll
                for (int i = 0; i < 4; ++i) {
                    int s = tid + i * 512;
                    int row = s >> 3, c4 = (s & 7) * 4;
                    float4 v = *reinterpret_cast<const float4*>(
                        &Wc[(size_t)(g0 + row) * HD + k0 + c4]);
                    Bs[(c4 + 0) * 260 + row] = v.x; Bs[(c4 + 1) * 260 + row] = v.y;
                    Bs[(c4 + 2) * 260 + row] = v.z; Bs[(c4 + 3) * 260 + row] = v.w;
                }
                __syncthreads();
                #pragma unroll
                for (int kk = 0; kk < 32; ++kk) {
                    float4 a0 = *reinterpret_cast<const float4*>(&As[kk * 68 + r]);
                    float4 a1 = *reinterpret_cast<const float4*>(&As[kk * 68 + r + 4]);
                    float4 bv = *reinterpret_cast<const float4*>(&Bs[kk * 260 + c]);
                    float a_[8] = {a0.x, a0.y, a0.z, a0.w, a1.x, a1.y, a1.z, a1.w};
                    float b_[4] = {bv.x, bv.y, bv.z, bv.w};
                    #pragma unroll
                    for (int i = 0; i < 8; ++i)
                        #pragma unroll
                        for (int j = 0; j < 4; ++j)
                            acc[i][j] += a_[i] * b_[j];
                }
                __syncthreads();
            }
            const size_t base = (size_t)t * GG * BB;
            #pragma unroll
            for (int j = 0; j < 4; ++j) {
                int g = g0 + c + j;
                float bias = bc[g];
                float4 v0 = {acc[0][j] + bias, acc[1][j] + bias,
                             acc[2][j] + bias, acc[3][j] + bias};
                float4 v1 = {acc[4][j] + bias, acc[5][j] + bias,
                             acc[6][j] + bias, acc[7][j] + bias};
                *reinterpret_cast<float4*>(&xg[base + (size_t)g * BB + r]) = v0;
                *reinterpret_cast<float4*>(&xg[base + (size_t)g * BB + r + 4]) = v1;
            }
            __syncthreads();   // all tile stores drained before publish
            if (tid == 0)
                __hip_atomic_fetch_add(&cnt[t], 1u, __ATOMIC_RELEASE,
                                       __HIP_MEMORY_SCOPE_AGENT);
        }
    }
}

// -------------------------------------------------------------------------
// out_last[b][o] = sum_k hfin[k][b] * W_out[o][k] + b_out[o]
__global__ __launch_bounds__(256) void k_out(const float* __restrict__ ht,
                                             const float* __restrict__ Wout,
                                             const float* __restrict__ bout,
                                             float* __restrict__ out) {
    __shared__ __align__(16) float hs[128][68];
    __shared__ __align__(16) float wsl[16][128];
    const int tid = threadIdx.x;
    const int o0 = blockIdx.x * 16;
    const int b = tid & 63;
    const int obase = tid >> 6;
    float acc[4] = {};
    for (int k0 = 0; k0 < HD; k0 += 128) {
        #pragma unroll
        for (int i = 0; i < 8; ++i) {
            int s = tid + i * 256;
            int k = s >> 4;
            int bb = (s & 15) * 4;
            float4 v = *reinterpret_cast<const float4*>(&ht[(size_t)k0 * 64 + (size_t)s * 4]);
            *reinterpret_cast<float4*>(&hs[k][bb]) = v;
        }
        for (int s = tid; s < 16 * 32; s += 256) {
            int rr = s >> 5;
            int c4 = (s & 31) * 4;
            float4 v = *reinterpret_cast<const float4*>(&Wout[(size_t)(o0 + rr) * HD + k0 + c4]);
            *reinterpret_cast<float4*>(&wsl[rr][c4]) = v;
        }
        __syncthreads();
        for (int kk = 0; kk < 128; kk += 4) {
            float hv[4];
            #pragma unroll
            for (int u = 0; u < 4; ++u) hv[u] = hs[kk + u][b];
            #pragma unroll
            for (int i = 0; i < 4; ++i) {
                float4 wv = *reinterpret_cast<const float4*>(&wsl[obase + 4 * i][kk]);
                acc[i] += hv[0] * wv.x + hv[1] * wv.y + hv[2] * wv.z + hv[3] * wv.w;
            }
        }
        __syncthreads();
    }
    #pragma unroll
    for (int i = 0; i < 4; ++i) {
        int o = o0 + obase + 4 * i;
        out[(size_t)b * 1024 + o] = acc[i] + bout[o];
    }
}

// hidden_out[b][h] = hfin[h][b], written at d_out + 65536
__global__ void k_hout(const float* __restrict__ ht, float* __restrict__ outp) {
    int idx = blockIdx.x * 256 + threadIdx.x;   // 65536
    int b = idx >> 10;
    int hh = idx & 1023;
    outp[idx] = ht[(size_t)hh * 64 + b];
}

// -------------------------------------------------------------------------
extern "C" void kernel_launch(void* const* d_in, const int* in_sizes, int n_in,
                              void* d_out, int out_size, void* d_ws, size_t ws_size,
                              hipStream_t stream) {
    (void)in_sizes; (void)n_in; (void)out_size; (void)ws_size;
    const float* wi     = (const float*)d_in[0];   // (B,T,1024)
    const float* hidden = (const float*)d_in[1];   // (1,B,H)
    const float* W_in   = (const float*)d_in[2];   // (H,1024)
    const float* b_in   = (const float*)d_in[3];
    const float* W_ih   = (const float*)d_in[4];   // (3H,H)
    const float* b_ih   = (const float*)d_in[5];
    const float* W_hh   = (const float*)d_in[6];   // (3H,H)
    const float* b_hh   = (const float*)d_in[7];
    const float* W_out  = (const float*)d_in[8];   // (1024,H)
    const float* b_out  = (const float*)d_in[9];

    char* ws = (char*)d_ws;
    float*    wcomb = (float*)(ws + OFF_WCOMB);
    float*    bcomb = (float*)(ws + OFF_BCOMB);
    float*    xg    = (float*)(ws + OFF_XG);
    __half*   hta   = (__half*)(ws + OFF_HTA);
    __half*   htb   = (__half*)(ws + OFF_HTB);
    float*    hfin  = (float*)(ws + OFF_HFIN);
    unsigned* bar   = (unsigned*)(ws + OFF_BAR);
    float*    out   = (float*)d_out;

    k_init<<<256, 256, 0, stream>>>(hidden, hta, bar);
    k_fold<<<dim3(48, 16), 256, 0, stream>>>(W_ih, W_in, wcomb);
    k_bcomb<<<768, 256, 0, stream>>>(W_ih, b_in, b_ih, bcomb);
    k_fused<<<256, 512, 0, stream>>>(W_hh, b_hh, wi, wcomb, bcomb, xg,
                                     hidden, hta, htb, hfin, bar);
    k_out<<<64, 256, 0, stream>>>(hfin, W_out, b_out, out);
    k_hout<<<256, 256, 0, stream>>>(hfin, out + 65536);
}